// Round 4
// baseline (306.544 us; speedup 1.0000x reference)
//
#include <hip/hip_runtime.h>
#include <hip/hip_bf16.h>
#include <stdint.h>

// LSTMCell fused: gates[8192,4096] = x@Wx^T + h@Wh^T + b as one NT-GEMM
// (M=8192, N=4096 via 4 gate-tiles, K=2048 = concat[x|h]), then elementwise.
// I/O: fp32. Compute: bf16 MFMA 16x16x32 (absmax 0.0156, verified r2-r6).
//
// r7: r6 fixed L2 locality (FETCH 287->115MB) but MfmaUtil stayed 37% ->
// staging latency was NOT the wall. The wall: sched_barrier(0)+clobbers
// pinned ALL ds_reads + address-VALU + DMA issue outside the MFMA clusters,
// in 8-wave lockstep (m141's measured order-pinning failure). This round:
//  - fragment reads for phase p+1 / tile t+1 issued INSIDE phase p's MFMA
//    region (4-deep buffers make RAW/WAR distinct; readiness barriers kept)
//  - sched_barrier(0) + explicit lgkmcnt(0) REMOVED (C++ ds_reads: the
//    compiler emits fine-grained lgkmcnt itself; rule-18 only applies to
//    inline-asm reads)
//  - 2 barriers/tile (was 4); counted vmcnt(6) once per tile
//  - all stage/read addressing hoisted to loop-invariant pointers
// Accumulation order is slot-identical to r6 -> bitwise-same result.
#define B_ROWS 8192
#define D_DIM  1024
#define H_DIM  1024
#define K_DIM  2048
#define N_GATES 4096

// fallback (r3) tile params
#define BM 128
#define BN 64
#define BK 64

#define KC (K_DIM / 32)        // 64 k32-chunks = # K-tiles (BK=32 in main)
#define A_M16 (B_ROWS / 16)    // 512 row-chunks
#define W_N16 (N_GATES / 16)   // 256 gate-row-chunks
#define A_CHUNKS (A_M16 * KC)  // 32768
#define W_CHUNKS (W_N16 * KC)  // 16384
#define A_WS_BYTES ((size_t)A_CHUNKS * 1024)
#define W_WS_BYTES ((size_t)W_CHUNKS * 1024)

// main kernel geometry
#define TBM 256                // rows per block
#define TBH 64                 // h-cols per block (x4 gates = 256 gate cols)
#define NT  KC                 // 64 K-tiles of 32
#define NBUF 4                 // LDS pipeline depth (prefetch distance 3)
#define SBUF (16 * 512)        // elements per LDS buffer (16 chunks)

typedef __bf16 bf16x8 __attribute__((ext_vector_type(8)));
typedef float  f32x4  __attribute__((ext_vector_type(4)));
using bf16_t = __hip_bfloat16;

__device__ __forceinline__ float sigm(float x) {
  return 1.0f / (1.0f + __expf(-x));
}
__device__ __forceinline__ float tanh_fast(float x) {
  return 1.0f - 2.0f / (__expf(2.0f * x) + 1.0f);  // no inf/inf NaN
}

__device__ __forceinline__ void async_ld16(const void* g, void* l) {
  __builtin_amdgcn_global_load_lds(
      (const __attribute__((address_space(1))) unsigned int*)g,
      (__attribute__((address_space(3))) unsigned int*)l, 16, 0, 0);
}

#define FENCE() asm volatile("" ::: "memory")
#define BAR() do { FENCE(); __builtin_amdgcn_s_barrier(); FENCE(); } while (0)

// ---- pack: fp32 inputs -> bf16, MFMA-frag-linear chunks -------------------
// Chunk = 16 rows x 32 k. Element (lane, j): row = base+(lane&15),
// k = kbase + (lane>>4)*8 + j. Stored at chunk*1024B + lane*16B + j*2B.
// This IS the 16x16x32 MFMA A/B operand layout: the main kernel's frag
// read is ds_read_b128 at chunkbase + lane*16: linear, conflict-free.
__global__ void pack_tiles(const float* __restrict__ x,
                           const float* __restrict__ h,
                           const float* __restrict__ Wx,
                           const float* __restrict__ Wh,
                           bf16_t* __restrict__ aws,
                           bf16_t* __restrict__ wws) {
  const int wave = threadIdx.x >> 6, lane = threadIdx.x & 63;
  int c = blockIdx.x * 4 + wave;   // 49152 chunks total, exact grid
  const int r16 = lane & 15, quad = lane >> 4;
  const float* src;
  size_t soff;
  bf16_t* dst;
  if (c < A_CHUNKS) {
    const int m16 = c / KC, k32 = c % KC;
    const int k = k32 * 32 + quad * 8;      // no x/h straddle: 32 | 1024
    src = (k < D_DIM) ? x : h;
    soff = (size_t)(m16 * 16 + r16) * 1024 + (k & 1023);
    dst = aws + (size_t)c * 512;
  } else {
    c -= A_CHUNKS;
    const int n16 = c / KC, k32 = c % KC;
    const int k = k32 * 32 + quad * 8;
    src = (k < D_DIM) ? Wx : Wh;
    soff = (size_t)(n16 * 16 + r16) * 1024 + (k & 1023);
    dst = wws + (size_t)c * 512;
  }
  const f32x4 a = *(const f32x4*)(src + soff);
  const f32x4 b = *(const f32x4*)(src + soff + 4);
  bf16x8 v;
#pragma unroll
  for (int i = 0; i < 4; ++i) { v[i] = (__bf16)a[i]; v[i + 4] = (__bf16)b[i]; }
  *(bf16x8*)(dst + lane * 8) = v;   // 1 KB/wave contiguous store
}

// ---- main: software-pipelined counted-vmcnt bf16 MFMA GEMM + LSTM epilogue
// 8 waves: wave tile = 128 rows x (16 h-cols x 4 gates). acc[g][mi] 128 AGPR.
// LDS: 4 buffers x (16 A + 16 B chunks) x 1KB = 128 KB, 1 block/CU.
// Per tile t, two regions separated by one barrier each:
//  R0: [issue af47(t) reads | stage A(t+3) | 16 MFMA(af03,bw)] vmcnt(6) BAR
//  R1: [issue af03/bw(t+1) reads | stage B(t+3) | 16 MFMA(af47,bw)]      BAR
// Every ds_read is issued one full MFMA region (~500cyc) before its use;
// compiler schedules reads/VALU among MFMAs (no sched_barrier pinning).
__global__ __launch_bounds__(512, 2) void lstm_mfma(
    const bf16_t* __restrict__ aws, const bf16_t* __restrict__ wws,
    const float* __restrict__ c_prev, const float* __restrict__ bias,
    float* __restrict__ h_out, float* __restrict__ c_out) {
  __shared__ __align__(16) bf16_t sA[NBUF * SBUF];   // 64 KB
  __shared__ __align__(16) bf16_t sB[NBUF * SBUF];   // 64 KB

  const int tid  = threadIdx.x;
  const int wave = tid >> 6;
  const int lane = tid & 63;

  // XCD mapping (bijective): 8 regions of 8m x 8n blocks (4 along m, 2
  // along n). Per-XCD footprint A 8MB + W 8MB in 256KB k-slices through
  // the 4MB L2. Verified r6: FETCH 115MB (~ideal A*2 + W*4).
  const int xcd = blockIdx.x & 7;
  const int idx = blockIdx.x >> 3;                  // 0..63 within region
  const int m_blk = (xcd >> 1) * 8 + (idx & 7);     // 0..31
  const int n_blk = (xcd & 1) * 8 + (idx >> 3);     // 0..15
  const int m0 = m_blk * TBM;
  const int n0 = n_blk * TBH;
  const int m16_0 = m0 >> 4;
  const int n16_0 = n0 >> 4;

  const int wm = wave >> 2;       // 0..1  (row half)
  const int wh = wave & 3;        // 0..3  (h-col quarter)
  const int lr = lane & 15, quad = lane >> 4;

  f32x4 acc[4][8];
#pragma unroll
  for (int g = 0; g < 4; ++g)
#pragma unroll
    for (int mi = 0; mi < 8; ++mi) {
      f32x4 z = {0.0f, 0.0f, 0.0f, 0.0f};
      acc[g][mi] = z;
    }

  // Loop-invariant stage pointers: chunk row fixed per wave, k-chunk tt
  // advances by +512 elements; LDS dest rotates over 4 buffers.
  const bf16_t* gA  = aws + (size_t)(m16_0 + wave) * KC * 512 + lane * 8;
  const bf16_t* gA8 = gA + (size_t)8 * KC * 512;
  const int n16w = (wave >> 2) * (H_DIM / 16) + n16_0 + (wave & 3);
  const bf16_t* gB  = wws + (size_t)n16w * KC * 512 + lane * 8;
  const bf16_t* gB8 = gB + (size_t)128 * KC * 512;   // j=wave+8 -> +2 gates
  bf16_t* lA  = sA + wave * 512 + lane * 8;
  bf16_t* lA8 = lA + 8 * 512;
  bf16_t* lB  = sB + wave * 512 + lane * 8;
  bf16_t* lB8 = lB + 8 * 512;

  auto STAGE_A = [&](int tt) {
    const int bo = (tt & 3) * SBUF;
    const size_t go = (size_t)tt * 512;
    async_ld16(gA + go, lA + bo);
    async_ld16(gA8 + go, lA8 + bo);
  };
  auto STAGE_B = [&](int tt) {
    const int bo = (tt & 3) * SBUF;
    const size_t go = (size_t)tt * 512;
    async_ld16(gB + go, lB + bo);
    async_ld16(gB8 + go, lB8 + bo);
  };

  const int rA = wm * 8 * 512 + lane * 8;   // + x*512 (+4*512 for ph1 half)
  const int rB = wh * 512 + lane * 8;       // + g*4*512

  auto LD_AF = [&](bf16x8 (&dst)[4], int bufo, int half4) {
#pragma unroll
    for (int x = 0; x < 4; ++x)
      dst[x] = *(const bf16x8*)&sA[bufo + rA + (half4 + x) * 512];
  };
  auto LD_BW = [&](bf16x8 (&dst)[4], int bufo) {
#pragma unroll
    for (int g = 0; g < 4; ++g)
      dst[g] = *(const bf16x8*)&sB[bufo + rB + g * 4 * 512];
  };
  auto MMA = [&](const bf16x8 (&a)[4], const bf16x8 (&b)[4], int s) {
    __builtin_amdgcn_s_setprio(1);
#pragma unroll
    for (int g = 0; g < 4; ++g)
#pragma unroll
      for (int x = 0; x < 4; ++x)
        acc[g][s + x] = __builtin_amdgcn_mfma_f32_16x16x32_bf16(
            a[x], b[g], acc[g][s + x], 0, 0, 0);
    __builtin_amdgcn_s_setprio(0);
  };

  // Prologue: stage tiles 0,1,2 (12 instrs/wave); wait tile 0 (oldest 4).
  STAGE_A(0); STAGE_B(0); STAGE_A(1); STAGE_B(1); STAGE_A(2); STAGE_B(2);
  asm volatile("s_waitcnt vmcnt(8)" ::: "memory");
  BAR();

  bf16x8 afA[4], bwA[4], afB[4], bwB[4];
  LD_AF(afA, 0, 0);
  LD_BW(bwA, 0);

  auto tile_step = [&](int t, bf16x8 (&afc)[4], bf16x8 (&bwc)[4],
                       bf16x8 (&afn)[4], bf16x8 (&bwn)[4]) {
    const int cbo = (t & 3) * SBUF;
    const int nbo = ((t + 1) & 3) * SBUF;
    bf16x8 af2[4];
    // ---- R0: MFMA(af03,bw) || read af47(t) || stage A(t+3) ----
    LD_AF(af2, cbo, 4);
    if (t + 3 < NT) STAGE_A(t + 3);
    MMA(afc, bwc, 0);
    // t+1 readiness (loads issued 4 regions ago); never 0 until tail.
    if (t + 3 < NT)      asm volatile("s_waitcnt vmcnt(6)" ::: "memory");
    else if (t + 2 < NT) asm volatile("s_waitcnt vmcnt(4)" ::: "memory");
    else if (t + 1 < NT) asm volatile("s_waitcnt vmcnt(0)" ::: "memory");
    BAR();
    // ---- R1: MFMA(af47,bw) || read af03/bw(t+1) || stage B(t+3) ----
    if (t + 1 < NT) { LD_AF(afn, nbo, 0); LD_BW(bwn, nbo); }
    if (t + 3 < NT) STAGE_B(t + 3);
    MMA(af2, bwc, 4);
    BAR();
  };

  for (int t = 0; t < NT; t += 2) {
    tile_step(t,     afA, bwA, afB, bwB);
    tile_step(t + 1, afB, bwB, afA, bwA);
  }

  // Epilogue: C/D layout col = lane&15 (gate col), row = quad*4 + reg.
  const int col = n0 + wh * 16 + lr;
  const float bi  = bias[col];
  const float bfv = bias[H_DIM + col];
  const float bo  = bias[2 * H_DIM + col];
  const float bg  = bias[3 * H_DIM + col];
#pragma unroll
  for (int mi = 0; mi < 8; ++mi) {
#pragma unroll
    for (int r = 0; r < 4; ++r) {
      const int m = m0 + wm * 128 + mi * 16 + quad * 4 + r;
      const size_t off = (size_t)m * H_DIM + col;
      const float iv = acc[0][mi][r] + bi;
      const float fv = acc[1][mi][r] + bfv;
      const float ov = acc[2][mi][r] + bo;
      const float gv = acc[3][mi][r] + bg;
      const float cp = c_prev[off];
      const float ct = sigm(fv) * cp + sigm(iv) * tanh_fast(gv);
      h_out[off] = sigm(ov) * tanh_fast(ct);
      c_out[off] = ct;
    }
  }
}

// ---- fallback (r3 kernel): used only if ws_size is too small --------------
__device__ __forceinline__ int sw_(int row, int chunk) {
  return row * BK + ((chunk ^ (row & 7)) << 3);
}

__global__ __launch_bounds__(256, 2) void lstm_f32(
    const float* __restrict__ x, const float* __restrict__ h_prev,
    const float* __restrict__ c_prev, const float* __restrict__ Wx,
    const float* __restrict__ Wh, const float* __restrict__ bias,
    float* __restrict__ h_out, float* __restrict__ c_out) {
  __shared__ bf16_t sA[BM * BK];
  __shared__ bf16_t sB[4 * BN * BK];
  const int tid = threadIdx.x, wave = tid >> 6, lane = tid & 63;
  const int m0 = blockIdx.x * BM, n0 = blockIdx.y * BN;
  const int wm = wave >> 1, wn = wave & 1;
  const int lr = lane & 15, quad = lane >> 4;
  f32x4 acc[4][4][2];
#pragma unroll
  for (int g = 0; g < 4; ++g)
#pragma unroll
    for (int ti = 0; ti < 4; ++ti)
#pragma unroll
      for (int tj = 0; tj < 2; ++tj) {
        f32x4 z = {0.0f, 0.0f, 0.0f, 0.0f};
        acc[g][ti][tj] = z;
      }
  const int srow = lane >> 3, lc = lane & 7, scol = lc << 3;
  for (int k0 = 0; k0 < K_DIM; k0 += BK) {
    const float* aSrc; const float* wSrc; int kh;
    if (k0 < D_DIM) { aSrc = x; wSrc = Wx; kh = k0; }
    else            { aSrc = h_prev; wSrc = Wh; kh = k0 - D_DIM; }
    f32x4 stg[12][2];
#pragma unroll
    for (int t = 0; t < 12; ++t) {
      const int chunk = wave + t * 4;
      const float* g;
      if (chunk < 16) {
        g = aSrc + (size_t)(m0 + chunk * 8 + srow) * 1024 + kh + scol;
      } else {
        const int j = chunk - 16;
        g = wSrc + (size_t)((j >> 3) * H_DIM + n0 + (j & 7) * 8 + srow) * 1024 + kh + scol;
      }
      stg[t][0] = *(const f32x4*)g;
      stg[t][1] = *(const f32x4*)(g + 4);
    }
    __syncthreads();
#pragma unroll
    for (int t = 0; t < 12; ++t) {
      const int chunk = wave + t * 4;
      bf16x8 v;
#pragma unroll
      for (int i = 0; i < 4; ++i) {
        v[i] = (__bf16)stg[t][0][i];
        v[i + 4] = (__bf16)stg[t][1][i];
      }
      bf16_t* dst;
      if (chunk < 16) dst = &sA[sw_(chunk * 8 + srow, lc)];
      else {
        const int j = chunk - 16;
        dst = &sB[(j >> 3) * (BN * BK) + sw_((j & 7) * 8 + srow, lc)];
      }
      *(bf16x8*)dst = v;
    }
    __syncthreads();
#pragma unroll
    for (int kk = 0; kk < BK; kk += 32) {
      const int cbase = kk >> 3;
      bf16x8 af[4];
#pragma unroll
      for (int ti = 0; ti < 4; ++ti)
        af[ti] = *(const bf16x8*)&sA[sw_(wm * 64 + ti * 16 + lr, cbase + quad)];
      bf16x8 bw[4][2];
#pragma unroll
      for (int g = 0; g < 4; ++g)
#pragma unroll
        for (int tj = 0; tj < 2; ++tj)
          bw[g][tj] = *(const bf16x8*)
              &sB[g * (BN * BK) + sw_(wn * 32 + tj * 16 + lr, cbase + quad)];
#pragma unroll
      for (int g = 0; g < 4; ++g)
#pragma unroll
        for (int ti = 0; ti < 4; ++ti)
#pragma unroll
          for (int tj = 0; tj < 2; ++tj)
            acc[g][ti][tj] = __builtin_amdgcn_mfma_f32_16x16x32_bf16(
                af[ti], bw[g][tj], acc[g][ti][tj], 0, 0, 0);
    }
  }
#pragma unroll
  for (int tj = 0; tj < 2; ++tj) {
    const int n = n0 + wn * 32 + tj * 16 + lr;
    const float bi = bias[n], bf = bias[H_DIM + n];
    const float bo = bias[2 * H_DIM + n], bg = bias[3 * H_DIM + n];
#pragma unroll
    for (int ti = 0; ti < 4; ++ti)
#pragma unroll
      for (int r = 0; r < 4; ++r) {
        const int m = m0 + wm * 64 + ti * 16 + quad * 4 + r;
        const size_t off = (size_t)m * H_DIM + n;
        const float iv = acc[0][ti][tj][r] + bi;
        const float fv = acc[1][ti][tj][r] + bf;
        const float ov = acc[2][ti][tj][r] + bo;
        const float gv = acc[3][ti][tj][r] + bg;
        const float cp = c_prev[off];
        const float ct = sigm(fv) * cp + sigm(iv) * tanh_fast(gv);
        h_out[off] = sigm(ov) * tanh_fast(ct);
        c_out[off] = ct;
      }
  }
}

extern "C" void kernel_launch(void* const* d_in, const int* in_sizes, int n_in,
                              void* d_out, int out_size, void* d_ws, size_t ws_size,
                              hipStream_t stream) {
  const float* x      = (const float*)d_in[0];
  const float* h_prev = (const float*)d_in[1];
  const float* c_prev = (const float*)d_in[2];
  const float* Wx     = (const float*)d_in[3];
  const float* Wh     = (const float*)d_in[4];
  const float* b      = (const float*)d_in[5];
  float* h_out = (float*)d_out;
  float* c_out = (float*)d_out + (size_t)B_ROWS * H_DIM;

  if (ws_size >= A_WS_BYTES + W_WS_BYTES) {
    bf16_t* aws = (bf16_t*)d_ws;
    bf16_t* wws = (bf16_t*)((char*)d_ws + A_WS_BYTES);
    pack_tiles<<<(A_CHUNKS + W_CHUNKS) / 4, 256, 0, stream>>>(x, h_prev, Wx, Wh,
                                                              aws, wws);
    const int nblk = (B_ROWS / TBM) * (H_DIM / TBH);   // 512
    lstm_mfma<<<nblk, 512, 0, stream>>>(aws, wws, c_prev, b, h_out, c_out);
  } else {
    dim3 grid(B_ROWS / BM, H_DIM / BN, 1);
    lstm_f32<<<grid, 256, 0, stream>>>(x, h_prev, c_prev, Wx, Wh, b, h_out, c_out);
  }
}

// Round 6
// 300.210 us; speedup vs baseline: 1.0211x; 1.0211x over previous
//
#include <hip/hip_runtime.h>
#include <hip/hip_bf16.h>
#include <stdint.h>

// LSTMCell fused: gates[8192,4096] = x@Wx^T + h@Wh^T + b as one NT-GEMM
// (M=8192, N=4096 via 4 gate-tiles, K=2048 = concat[x|h]), then elementwise.
// I/O: fp32. Compute: bf16 MFMA 16x16x32 (absmax 0.0156, verified r2-r7).
//
// r9 == r8 resubmitted (round-5 bench was the same "container failed twice"
// infra error as round 2, which on resubmission ran clean and passed; audit
// of the r8 diff found no hang-capable defect: pack has no barriers/waits,
// bounds exact, bijective bpermute, GEMM byte-identical to the r7 run).
//
// r8 rationale: GEMM stable at 154us across 3 schedule variants (MfmaUtil
// 39% = 43% of the per-SIMD 16x16-pipe floor). The unattacked cost:
// dur_us - lstm_mfma ~= 140-150us every round = pack_tiles, vs a 23us
// roofline (144MB @ 6.3TB/s). Cause: old pack read 32B/lane at 4KB stride
// (lane=row) -> 64 scattered requests/wave. Rewrite pack only: coalesced
// reads (4 lanes tile each 128B line) + 4x ds_bpermute to the frag lane
// order. Emitted bytes BIT-IDENTICAL -> GEMM & absmax untouched.
#define B_ROWS 8192
#define D_DIM  1024
#define H_DIM  1024
#define K_DIM  2048
#define N_GATES 4096

// fallback (r3) tile params
#define BM 128
#define BN 64
#define BK 64

#define KC (K_DIM / 32)        // 64 k32-chunks = # K-tiles (BK=32 in main)
#define A_M16 (B_ROWS / 16)    // 512 row-chunks
#define W_N16 (N_GATES / 16)   // 256 gate-row-chunks
#define A_CHUNKS (A_M16 * KC)  // 32768
#define W_CHUNKS (W_N16 * KC)  // 16384
#define A_WS_BYTES ((size_t)A_CHUNKS * 1024)
#define W_WS_BYTES ((size_t)W_CHUNKS * 1024)

// main kernel geometry
#define TBM 256                // rows per block
#define TBH 64                 // h-cols per block (x4 gates = 256 gate cols)
#define NT  KC                 // 64 K-tiles of 32
#define NBUF 4                 // LDS pipeline depth (prefetch distance 3)
#define SBUF (16 * 512)        // elements per LDS buffer (16 chunks)

typedef __bf16 bf16x8 __attribute__((ext_vector_type(8)));
typedef float  f32x4  __attribute__((ext_vector_type(4)));
typedef int    i32x4  __attribute__((ext_vector_type(4)));
using bf16_t = __hip_bfloat16;

__device__ __forceinline__ float sigm(float x) {
  return 1.0f / (1.0f + __expf(-x));
}
__device__ __forceinline__ float tanh_fast(float x) {
  return 1.0f - 2.0f / (__expf(2.0f * x) + 1.0f);  // no inf/inf NaN
}

__device__ __forceinline__ void async_ld16(const void* g, void* l) {
  __builtin_amdgcn_global_load_lds(
      (const __attribute__((address_space(1))) unsigned int*)g,
      (__attribute__((address_space(3))) unsigned int*)l, 16, 0, 0);
}

#define FENCE() asm volatile("" ::: "memory")
#define BAR() do { FENCE(); __builtin_amdgcn_s_barrier(); FENCE(); } while (0)

// ---- pack: fp32 inputs -> bf16, MFMA-frag-linear chunks (coalesced) -------
// Chunk = 16 rows x 32 k. Frag element (lane T, j): row = T&15,
// k = kbase + (T>>4)*8 + j; stored at chunk*1024B + T*16B + j*2B.
// Read side (coalesced): lane L reads 32B contiguous at row = L>>2,
// k = kbase + (L&3)*8 -> 4 lanes cover each 128B line exactly; 16 lines
// per chunk, all fully consumed. Redistribute to frag order with 4x
// ds_bpermute: out[T] pulls from L(T) = ((T&15)<<2) | (T>>4).
// (L(T)&3 == T>>4 gives the right k-quad; L(T)>>2 == T&15 the right row.)
// Same source elements, same (__bf16) cast, same layout as r0-r7 pack ->
// bit-identical workspace bytes.
__global__ __launch_bounds__(256) void pack_tiles(
    const float* __restrict__ x, const float* __restrict__ h,
    const float* __restrict__ Wx, const float* __restrict__ Wh,
    bf16_t* __restrict__ aws, bf16_t* __restrict__ wws) {
  const int wave = threadIdx.x >> 6, lane = threadIdx.x & 63;
  const int row = lane >> 2;                       // source row within chunk
  const int kq  = lane & 3;                        // source k-quad (8 f32)
  const int LT4 = (((lane & 15) << 2) | (lane >> 4)) << 2;  // bpermute addr
  const int c0 = (blockIdx.x * 4 + wave) * 4;      // 4 chunks per wave

#pragma unroll
  for (int cc = 0; cc < 4; ++cc) {
    int c = c0 + cc;
    const float* src;
    size_t soff;
    bf16_t* dst;
    if (c < A_CHUNKS) {
      const int m16 = c / KC, k32 = c % KC;
      const int k = k32 * 32 + kq * 8;             // no x/h straddle: 32|1024
      src = (k < D_DIM) ? x : h;
      soff = (size_t)(m16 * 16 + row) * 1024 + (k & 1023);
      dst = aws + (size_t)c * 512;
    } else {
      const int cw = c - A_CHUNKS;
      const int n16 = cw / KC, k32 = cw % KC;
      const int k = k32 * 32 + kq * 8;
      src = (k < D_DIM) ? Wx : Wh;
      soff = (size_t)(n16 * 16 + row) * 1024 + (k & 1023);
      dst = wws + (size_t)cw * 512;
    }
    const f32x4 a = *(const f32x4*)(src + soff);        // 32B/lane contiguous
    const f32x4 b = *(const f32x4*)(src + soff + 4);
    bf16x8 v;
#pragma unroll
    for (int i = 0; i < 4; ++i) { v[i] = (__bf16)a[i]; v[i + 4] = (__bf16)b[i]; }
    const i32x4 w = __builtin_bit_cast(i32x4, v);
    i32x4 p;
    p[0] = __builtin_amdgcn_ds_bpermute(LT4, w[0]);
    p[1] = __builtin_amdgcn_ds_bpermute(LT4, w[1]);
    p[2] = __builtin_amdgcn_ds_bpermute(LT4, w[2]);
    p[3] = __builtin_amdgcn_ds_bpermute(LT4, w[3]);
    *(i32x4*)(dst + lane * 8) = p;                 // 1 KB/wave contiguous
  }
}

// ---- main: software-pipelined counted-vmcnt bf16 MFMA GEMM + LSTM epilogue
// (unchanged from r7; 154us, MfmaUtil 39%, FETCH 115MB, 0 bank conflicts)
__global__ __launch_bounds__(512, 2) void lstm_mfma(
    const bf16_t* __restrict__ aws, const bf16_t* __restrict__ wws,
    const float* __restrict__ c_prev, const float* __restrict__ bias,
    float* __restrict__ h_out, float* __restrict__ c_out) {
  __shared__ __align__(16) bf16_t sA[NBUF * SBUF];   // 64 KB
  __shared__ __align__(16) bf16_t sB[NBUF * SBUF];   // 64 KB

  const int tid  = threadIdx.x;
  const int wave = tid >> 6;
  const int lane = tid & 63;

  // XCD mapping (bijective): 8 regions of 8m x 8n blocks (4 along m, 2
  // along n). Verified r6: FETCH 115MB (~ideal A*2 + W*4).
  const int xcd = blockIdx.x & 7;
  const int idx = blockIdx.x >> 3;                  // 0..63 within region
  const int m_blk = (xcd >> 1) * 8 + (idx & 7);     // 0..31
  const int n_blk = (xcd & 1) * 8 + (idx >> 3);     // 0..15
  const int m0 = m_blk * TBM;
  const int n0 = n_blk * TBH;
  const int m16_0 = m0 >> 4;
  const int n16_0 = n0 >> 4;

  const int wm = wave >> 2;       // 0..1  (row half)
  const int wh = wave & 3;        // 0..3  (h-col quarter)
  const int lr = lane & 15, quad = lane >> 4;

  f32x4 acc[4][8];
#pragma unroll
  for (int g = 0; g < 4; ++g)
#pragma unroll
    for (int mi = 0; mi < 8; ++mi) {
      f32x4 z = {0.0f, 0.0f, 0.0f, 0.0f};
      acc[g][mi] = z;
    }

  // Loop-invariant stage pointers: chunk row fixed per wave, k-chunk tt
  // advances by +512 elements; LDS dest rotates over 4 buffers.
  const bf16_t* gA  = aws + (size_t)(m16_0 + wave) * KC * 512 + lane * 8;
  const bf16_t* gA8 = gA + (size_t)8 * KC * 512;
  const int n16w = (wave >> 2) * (H_DIM / 16) + n16_0 + (wave & 3);
  const bf16_t* gB  = wws + (size_t)n16w * KC * 512 + lane * 8;
  const bf16_t* gB8 = gB + (size_t)128 * KC * 512;   // j=wave+8 -> +2 gates
  bf16_t* lA  = sA + wave * 512 + lane * 8;
  bf16_t* lA8 = lA + 8 * 512;
  bf16_t* lB  = sB + wave * 512 + lane * 8;
  bf16_t* lB8 = lB + 8 * 512;

  auto STAGE_A = [&](int tt) {
    const int bo = (tt & 3) * SBUF;
    const size_t go = (size_t)tt * 512;
    async_ld16(gA + go, lA + bo);
    async_ld16(gA8 + go, lA8 + bo);
  };
  auto STAGE_B = [&](int tt) {
    const int bo = (tt & 3) * SBUF;
    const size_t go = (size_t)tt * 512;
    async_ld16(gB + go, lB + bo);
    async_ld16(gB8 + go, lB8 + bo);
  };

  const int rA = wm * 8 * 512 + lane * 8;   // + x*512 (+4*512 for ph1 half)
  const int rB = wh * 512 + lane * 8;       // + g*4*512

  auto LD_AF = [&](bf16x8 (&dst)[4], int bufo, int half4) {
#pragma unroll
    for (int x = 0; x < 4; ++x)
      dst[x] = *(const bf16x8*)&sA[bufo + rA + (half4 + x) * 512];
  };
  auto LD_BW = [&](bf16x8 (&dst)[4], int bufo) {
#pragma unroll
    for (int g = 0; g < 4; ++g)
      dst[g] = *(const bf16x8*)&sB[bufo + rB + g * 4 * 512];
  };
  auto MMA = [&](const bf16x8 (&a)[4], const bf16x8 (&b)[4], int s) {
    __builtin_amdgcn_s_setprio(1);
#pragma unroll
    for (int g = 0; g < 4; ++g)
#pragma unroll
      for (int x = 0; x < 4; ++x)
        acc[g][s + x] = __builtin_amdgcn_mfma_f32_16x16x32_bf16(
            a[x], b[g], acc[g][s + x], 0, 0, 0);
    __builtin_amdgcn_s_setprio(0);
  };

  // Prologue: stage tiles 0,1,2 (12 instrs/wave); wait tile 0 (oldest 4).
  STAGE_A(0); STAGE_B(0); STAGE_A(1); STAGE_B(1); STAGE_A(2); STAGE_B(2);
  asm volatile("s_waitcnt vmcnt(8)" ::: "memory");
  BAR();

  bf16x8 afA[4], bwA[4], afB[4], bwB[4];
  LD_AF(afA, 0, 0);
  LD_BW(bwA, 0);

  auto tile_step = [&](int t, bf16x8 (&afc)[4], bf16x8 (&bwc)[4],
                       bf16x8 (&afn)[4], bf16x8 (&bwn)[4]) {
    const int cbo = (t & 3) * SBUF;
    const int nbo = ((t + 1) & 3) * SBUF;
    bf16x8 af2[4];
    // ---- R0: MFMA(af03,bw) || read af47(t) || stage A(t+3) ----
    LD_AF(af2, cbo, 4);
    if (t + 3 < NT) STAGE_A(t + 3);
    MMA(afc, bwc, 0);
    // t+1 readiness (loads issued 4 regions ago); never 0 until tail.
    if (t + 3 < NT)      asm volatile("s_waitcnt vmcnt(6)" ::: "memory");
    else if (t + 2 < NT) asm volatile("s_waitcnt vmcnt(4)" ::: "memory");
    else if (t + 1 < NT) asm volatile("s_waitcnt vmcnt(0)" ::: "memory");
    BAR();
    // ---- R1: MFMA(af47,bw) || read af03/bw(t+1) || stage B(t+3) ----
    if (t + 1 < NT) { LD_AF(afn, nbo, 0); LD_BW(bwn, nbo); }
    if (t + 3 < NT) STAGE_B(t + 3);
    MMA(af2, bwc, 4);
    BAR();
  };

  for (int t = 0; t < NT; t += 2) {
    tile_step(t,     afA, bwA, afB, bwB);
    tile_step(t + 1, afB, bwB, afA, bwA);
  }

  // Epilogue: C/D layout col = lane&15 (gate col), row = quad*4 + reg.
  const int col = n0 + wh * 16 + lr;
  const float bi  = bias[col];
  const float bfv = bias[H_DIM + col];
  const float bo  = bias[2 * H_DIM + col];
  const float bg  = bias[3 * H_DIM + col];
#pragma unroll
  for (int mi = 0; mi < 8; ++mi) {
#pragma unroll
    for (int r = 0; r < 4; ++r) {
      const int m = m0 + wm * 128 + mi * 16 + quad * 4 + r;
      const size_t off = (size_t)m * H_DIM + col;
      const float iv = acc[0][mi][r] + bi;
      const float fv = acc[1][mi][r] + bfv;
      const float ov = acc[2][mi][r] + bo;
      const float gv = acc[3][mi][r] + bg;
      const float cp = c_prev[off];
      const float ct = sigm(fv) * cp + sigm(iv) * tanh_fast(gv);
      h_out[off] = sigm(ov) * tanh_fast(ct);
      c_out[off] = ct;
    }
  }
}

// ---- fallback (r3 kernel): used only if ws_size is too small --------------
__device__ __forceinline__ int sw_(int row, int chunk) {
  return row * BK + ((chunk ^ (row & 7)) << 3);
}

__global__ __launch_bounds__(256, 2) void lstm_f32(
    const float* __restrict__ x, const float* __restrict__ h_prev,
    const float* __restrict__ c_prev, const float* __restrict__ Wx,
    const float* __restrict__ Wh, const float* __restrict__ bias,
    float* __restrict__ h_out, float* __restrict__ c_out) {
  __shared__ bf16_t sA[BM * BK];
  __shared__ bf16_t sB[4 * BN * BK];
  const int tid = threadIdx.x, wave = tid >> 6, lane = tid & 63;
  const int m0 = blockIdx.x * BM, n0 = blockIdx.y * BN;
  const int wm = wave >> 1, wn = wave & 1;
  const int lr = lane & 15, quad = lane >> 4;
  f32x4 acc[4][4][2];
#pragma unroll
  for (int g = 0; g < 4; ++g)
#pragma unroll
    for (int ti = 0; ti < 4; ++ti)
#pragma unroll
      for (int tj = 0; tj < 2; ++tj) {
        f32x4 z = {0.0f, 0.0f, 0.0f, 0.0f};
        acc[g][ti][tj] = z;
      }
  const int srow = lane >> 3, lc = lane & 7, scol = lc << 3;
  for (int k0 = 0; k0 < K_DIM; k0 += BK) {
    const float* aSrc; const float* wSrc; int kh;
    if (k0 < D_DIM) { aSrc = x; wSrc = Wx; kh = k0; }
    else            { aSrc = h_prev; wSrc = Wh; kh = k0 - D_DIM; }
    f32x4 stg[12][2];
#pragma unroll
    for (int t = 0; t < 12; ++t) {
      const int chunk = wave + t * 4;
      const float* g;
      if (chunk < 16) {
        g = aSrc + (size_t)(m0 + chunk * 8 + srow) * 1024 + kh + scol;
      } else {
        const int j = chunk - 16;
        g = wSrc + (size_t)((j >> 3) * H_DIM + n0 + (j & 7) * 8 + srow) * 1024 + kh + scol;
      }
      stg[t][0] = *(const f32x4*)g;
      stg[t][1] = *(const f32x4*)(g + 4);
    }
    __syncthreads();
#pragma unroll
    for (int t = 0; t < 12; ++t) {
      const int chunk = wave + t * 4;
      bf16x8 v;
#pragma unroll
      for (int i = 0; i < 4; ++i) {
        v[i] = (__bf16)stg[t][0][i];
        v[i + 4] = (__bf16)stg[t][1][i];
      }
      bf16_t* dst;
      if (chunk < 16) dst = &sA[sw_(chunk * 8 + srow, lc)];
      else {
        const int j = chunk - 16;
        dst = &sB[(j >> 3) * (BN * BK) + sw_((j & 7) * 8 + srow, lc)];
      }
      *(bf16x8*)dst = v;
    }
    __syncthreads();
#pragma unroll
    for (int kk = 0; kk < BK; kk += 32) {
      const int cbase = kk >> 3;
      bf16x8 af[4];
#pragma unroll
      for (int ti = 0; ti < 4; ++ti)
        af[ti] = *(const bf16x8*)&sA[sw_(wm * 64 + ti * 16 + lr, cbase + quad)];
      bf16x8 bw[4][2];
#pragma unroll
      for (int g = 0; g < 4; ++g)
#pragma unroll
        for (int tj = 0; tj < 2; ++tj)
          bw[g][tj] = *(const bf16x8*)
              &sB[g * (BN * BK) + sw_(wn * 32 + tj * 16 + lr, cbase + quad)];
#pragma unroll
      for (int g = 0; g < 4; ++g)
#pragma unroll
        for (int ti = 0; ti < 4; ++ti)
#pragma unroll
          for (int tj = 0; tj < 2; ++tj)
            acc[g][ti][tj] = __builtin_amdgcn_mfma_f32_16x16x32_bf16(
                af[ti], bw[g][tj], acc[g][ti][tj], 0, 0, 0);
    }
  }
#pragma unroll
  for (int tj = 0; tj < 2; ++tj) {
    const int n = n0 + wn * 32 + tj * 16 + lr;
    const float bi = bias[n], bf = bias[H_DIM + n];
    const float bo = bias[2 * H_DIM + n], bg = bias[3 * H_DIM + n];
#pragma unroll
    for (int ti = 0; ti < 4; ++ti)
#pragma unroll
      for (int r = 0; r < 4; ++r) {
        const int m = m0 + wm * 64 + ti * 16 + quad * 4 + r;
        const size_t off = (size_t)m * H_DIM + n;
        const float iv = acc[0][ti][tj][r] + bi;
        const float fv = acc[1][ti][tj][r] + bf;
        const float ov = acc[2][ti][tj][r] + bo;
        const float gv = acc[3][ti][tj][r] + bg;
        const float cp = c_prev[off];
        const float ct = sigm(fv) * cp + sigm(iv) * tanh_fast(gv);
        h_out[off] = sigm(ov) * tanh_fast(ct);
        c_out[off] = ct;
      }
  }
}

extern "C" void kernel_launch(void* const* d_in, const int* in_sizes, int n_in,
                              void* d_out, int out_size, void* d_ws, size_t ws_size,
                              hipStream_t stream) {
  const float* x      = (const float*)d_in[0];
  const float* h_prev = (const float*)d_in[1];
  const float* c_prev = (const float*)d_in[2];
  const float* Wx     = (const float*)d_in[3];
  const float* Wh     = (const float*)d_in[4];
  const float* b      = (const float*)d_in[5];
  float* h_out = (float*)d_out;
  float* c_out = (float*)d_out + (size_t)B_ROWS * H_DIM;

  if (ws_size >= A_WS_BYTES + W_WS_BYTES) {
    bf16_t* aws = (bf16_t*)d_ws;
    bf16_t* wws = (bf16_t*)((char*)d_ws + A_WS_BYTES);
    // 4 waves x 4 chunks per block -> 16 chunks/block; 49152/16 = 3072 blocks
    pack_tiles<<<(A_CHUNKS + W_CHUNKS) / 16, 256, 0, stream>>>(x, h_prev, Wx,
                                                               Wh, aws, wws);
    const int nblk = (B_ROWS / TBM) * (H_DIM / TBH);   // 512
    lstm_mfma<<<nblk, 512, 0, stream>>>(aws, wws, c_prev, b, h_out, c_out);
  } else {
    dim3 grid(B_ROWS / BM, H_DIM / BN, 1);
    lstm_f32<<<grid, 256, 0, stream>>>(x, h_prev, c_prev, Wx, Wh, b, h_out, c_out);
  }
}